// Round 9
// baseline (87.847 us; speedup 1.0000x reference)
//
#include <hip/hip_runtime.h>
#include <math.h>

// B=16, N=2048, M=32, P=48, T=5, C=240
#define NN 2048
#define MM 32
#define PP 48
#define CC 240
#define PI_F 3.14159265358979323846f
#define LOG2E_F 1.4426950408889634f

// One block per n: 256 threads = 4 waves; wave w owns b in {w, w+4, w+8, w+12}.
// Streaming Nbrs/NbrsZ loads + X gather are issued FIRST, into registers,
// before any LDS write or barrier (compiler can't hoist loads over s_barrier,
// so the preamble would otherwise delay the kernel's dominant HBM burst).
// Lane l -> filter p = l (lanes 48..63 duplicate p=l-48, discarded).
// Neighbors counting-sorted by type in LDS; R > max(rc) dropped (exact 0).
// fc = cos^2(pi R/(2 rc)); exp2 with log2e folded; raw v_cos_f32 in
// revolutions (coeff 0.25/rc, clamp 0.25 rev). Segment bounds -> SGPRs.
__global__ __launch_bounds__(256) void acp_fused(
    const float* __restrict__ X,      // [B,N,3]
    const float* __restrict__ rc,     // [P]
    const float* __restrict__ rs,     // [P]
    const float* __restrict__ re,     // [P]
    const int*   __restrict__ Nbrs,   // [B,N,M]
    const int*   __restrict__ NbrsZ,  // [B,N,M]
    float* __restrict__ out)          // [B,N,240]
{
    __shared__ float sRs[16 * 33];    // type-sorted R per b, stride 33
    __shared__ int   sCnt[16 * 8];
    __shared__ int   sBase[16 * 8];
    __shared__ float sPrs[PP], sPre[PP], sPp2[PP];
    __shared__ float sRcMax;
    __shared__ float redS, redQ;

    const int tid  = threadIdx.x;
    const int n    = blockIdx.x;
    const int lane = tid & 63;
    const int wv   = tid >> 6;        // wave 0..3

    // ---- Hoisted global reads: issue before ANY LDS/barrier ----
    int nbv[2], zv[2], tv[2], cv[2];
    #pragma unroll
    for (int k = 0; k < 2; ++k) {
        int slot = tid + k * 256;     // 0..511
        int c  = slot >> 5;           // b index 0..15
        int m  = slot & 31;
        cv[k] = c;
        int bn = c * NN + n;
        nbv[k] = Nbrs[bn * MM + m];   // coalesced dword
        zv[k]  = NbrsZ[bn * MM + m];  // coalesced dword
    }
    float Rv[2];
    #pragma unroll
    for (int k = 0; k < 2; ++k) {
        int z = zv[k];
        int t = (z == 1) ? 0 : (z == 6) ? 1 : (z == 7) ? 2
              : (z == 8) ? 3 : (z == 16) ? 4 : -1;
        tv[k] = t;
        Rv[k] = 0.0f;
        if (t >= 0) {                 // gather only valid (~29%) neighbors
            int bn = cv[k] * NN + n;
            const float* xo = X + (size_t)bn * 3;
            const float* xn = X + (size_t)(cv[k] * NN + nbv[k]) * 3;
            float dx = xn[0] - xo[0];
            float dy = xn[1] - xo[1];
            float dz = xn[2] - xo[2];
            Rv[k] = sqrtf(dx * dx + dy * dy + dz * dz);
        }
    }

    // ---- Preamble (overlaps with the loads above in other waves) ----
    if (tid < PP) {
        sPrs[tid] = rs[tid];
        sPre[tid] = -re[tid] * LOG2E_F;        // exp(-re d^2)=exp2(sPre d^2)
        sPp2[tid] = 0.25f / rc[tid];           // revolutions coefficient
    }
    if (wv == 0) {                             // max rc via wave-0 butterfly
        float v = (lane < PP) ? rc[lane] : 0.0f;
        #pragma unroll
        for (int k = 1; k < 64; k <<= 1) v = fmaxf(v, __shfl_xor(v, k, 64));
        if (lane == 0) sRcMax = v;
    }
    if (tid == 0) { redS = 0.0f; redQ = 0.0f; }
    if (tid < 128) sCnt[tid] = 0;
    __syncthreads();

    // ---- Phase 1: cutoff filter + counting-sort ----
    const float rcmax = sRcMax;
    int posv[2];
    #pragma unroll
    for (int k = 0; k < 2; ++k) {
        if (tv[k] >= 0 && Rv[k] <= rcmax)
            posv[k] = atomicAdd(&sCnt[cv[k] * 8 + tv[k]], 1);
        else
            tv[k] = -1;               // beyond every cutoff -> exact zero
    }
    __syncthreads();
    if (tid < 16) {
        int s = 0;
        #pragma unroll
        for (int t = 0; t < 5; ++t) { sBase[tid * 8 + t] = s; s += sCnt[tid * 8 + t]; }
    }
    __syncthreads();
    #pragma unroll
    for (int k = 0; k < 2; ++k)
        if (tv[k] >= 0)
            sRs[cv[k] * 33 + sBase[cv[k] * 8 + tv[k]] + posv[k]] = Rv[k];
    __syncthreads();

    // ---- Phase 2: scalar-bound segmented loops, lane = filter p ----
    const int p = (lane < PP) ? lane : lane - PP;
    const float prs = sPrs[p];
    const float pre = sPre[p];
    const float pp2 = sPp2[p];

    float acc[4][5];
    #pragma unroll
    for (int g = 0; g < 4; ++g) {
        const int c = wv + g * 4;
        const float* Rrow = sRs + c * 33;
        #pragma unroll
        for (int t = 0; t < 5; ++t) {
            // wave-uniform bounds -> force into SGPRs: scalar loop control
            int s = __builtin_amdgcn_readfirstlane(sBase[c * 8 + t]);
            int e = s + __builtin_amdgcn_readfirstlane(sCnt[c * 8 + t]);
            float a = 0.0f;
            for (int m = s; m < e; ++m) {
                float R  = Rrow[m];            // broadcast LDS read
                float d  = R - prs;
                float w  = __builtin_amdgcn_exp2f(pre * d * d);
                float ct = __builtin_amdgcn_cosf(fminf(R * pp2, 0.25f));
                a = fmaf(w * ct, ct, a);       // w * cos^2
            }
            acc[g][t] = a;
        }
    }

    // ---- Epilogue: fused BatchNorm stats (per n over 16 b x 240 c) ----
    float s1 = 0.0f, s2 = 0.0f;
    if (lane < PP) {
        #pragma unroll
        for (int g = 0; g < 4; ++g)
            #pragma unroll
            for (int t = 0; t < 5; ++t) {
                float v = acc[g][t];
                s1 += v;
                s2 = fmaf(v, v, s2);
            }
    }
    #pragma unroll
    for (int k = 1; k < 64; k <<= 1) {
        s1 += __shfl_xor(s1, k, 64);
        s2 += __shfl_xor(s2, k, 64);
    }
    if (lane == 0) {
        atomicAdd(&redS, s1);
        atomicAdd(&redQ, s2);
    }
    __syncthreads();

    const float cnt_inv = 1.0f / 3840.0f;
    float mean = redS * cnt_inv;
    float var  = redQ * cnt_inv - mean * mean;
    float rstd = rsqrtf(var + 1e-5f);

    if (lane < PP) {
        #pragma unroll
        for (int g = 0; g < 4; ++g) {
            const int c = wv + g * 4;
            float* o = out + ((size_t)c * NN + n) * CC + p;
            #pragma unroll
            for (int t = 0; t < 5; ++t)
                o[t * PP] = (acc[g][t] - mean) * rstd;
        }
    }
}

extern "C" void kernel_launch(void* const* d_in, const int* in_sizes, int n_in,
                              void* d_out, int out_size, void* d_ws, size_t ws_size,
                              hipStream_t stream) {
    const float* X     = (const float*)d_in[0];
    const float* rc    = (const float*)d_in[1];
    const float* rs    = (const float*)d_in[2];
    const float* re    = (const float*)d_in[3];
    const int*   Nbrs  = (const int*)d_in[4];
    const int*   NbrsZ = (const int*)d_in[5];
    float* out = (float*)d_out;

    acp_fused<<<NN, 256, 0, stream>>>(X, rc, rs, re, Nbrs, NbrsZ, out);
}